// Round 3
// baseline (936.937 us; speedup 1.0000x reference)
//
#include <hip/hip_runtime.h>
#include <hip/hip_bf16.h>
#include <stdint.h>

using u32 = unsigned int;
using u64 = unsigned long long;
using bf16 = __hip_bfloat16;
typedef __attribute__((ext_vector_type(8))) short short8;
typedef __attribute__((ext_vector_type(4))) float f32x4;
typedef __attribute__((ext_vector_type(8))) _Float16 half8;

constexpr int cB = 4096;   // batch
constexpr int cF = 4096;   // feat dim
constexpr int cH = 1024;   // enc hidden
constexpr int cL = 512;    // latent
constexpr int cK = 8192;   // codebook size
constexpr float MARGIN = 0.02f;  // >> max coarse bf16 distance error (~2.5e-3)

// monotone float->u32 key (ascending order preserved)
__device__ inline u32 monoKey(float d) {
    u32 u = __float_as_uint(d);
    return (u & 0x80000000u) ? ~u : (u | 0x80000000u);
}
__device__ inline float keyToFloat(u32 k) {
    u32 u = (k & 0x80000000u) ? (k ^ 0x80000000u) : ~k;
    return __uint_as_float(u);
}

__device__ inline u64 shflxor_u64_w16(u64 v, int mask) {
    u32 lo = (u32)v, hi = (u32)(v >> 32);
    lo = (u32)__shfl_xor((int)lo, mask, 16);
    hi = (u32)__shfl_xor((int)hi, mask, 16);
    return ((u64)hi << 32) | lo;
}

// async global->LDS, 16B per lane. LDS dest must be linear in lane order
// (wave-uniform base + lane*16) -- our staging layout satisfies this.
__device__ inline void gload16(const void* g, void* s) {
    __builtin_amdgcn_global_load_lds(
        (__attribute__((address_space(1))) void*)(void*)g,
        (__attribute__((address_space(3))) void*)s, 16, 0, 0);
}

// ---------------------------------------------------------------------------
// fp32-via-fp16 split helpers: x = hi + lo, hi=fp16(x), lo=fp16(x-hi).
// hi*hi' + lo*hi' + hi*lo' reproduces x*x' to ~2^-22 relative (fp32-level).
// ---------------------------------------------------------------------------

// elementwise split: in fp32 [n] -> hi/lo fp16 planes. 8 elts/thread.
__global__ __launch_bounds__(256)
void split_f16(const float* __restrict__ in, _Float16* __restrict__ hi,
               _Float16* __restrict__ lo) {
    size_t base = ((size_t)blockIdx.x * 256 + threadIdx.x) * 8;
    float4 a = *(const float4*)(in + base);
    float4 b = *(const float4*)(in + base + 4);
    float v[8] = {a.x, a.y, a.z, a.w, b.x, b.y, b.z, b.w};
    half8 h, l;
#pragma unroll
    for (int i = 0; i < 8; ++i) {
        _Float16 hh = (_Float16)v[i];
        h[i] = hh;
        l[i] = (_Float16)(v[i] - (float)hh);
    }
    *(half8*)(hi + base) = h;
    *(half8*)(lo + base) = l;
}

// transpose + split: oh/ol[c][r] = split(in[r][c])
__global__ __launch_bounds__(256)
void transpose_split(const float* __restrict__ in, _Float16* __restrict__ oh,
                     _Float16* __restrict__ ol, int R, int C) {
    __shared__ float tile[32][33];
    int c0 = blockIdx.x * 32, r0 = blockIdx.y * 32;
    int tx = threadIdx.x & 31, ty = threadIdx.x >> 5;
#pragma unroll
    for (int i = 0; i < 4; ++i) {
        int rr = ty + i * 8;
        tile[rr][tx] = in[(size_t)(r0 + rr) * C + c0 + tx];
    }
    __syncthreads();
#pragma unroll
    for (int i = 0; i < 4; ++i) {
        int a = ty + i * 8;
        float v = tile[tx][a];
        _Float16 hh = (_Float16)v;
        size_t o = (size_t)(c0 + a) * R + r0 + tx;
        oh[o] = hh;
        ol[o] = (_Float16)(v - (float)hh);
    }
}

// ---------------------------------------------------------------------------
// Direct (16-bit operand) staging via global_load_lds, width 16B.
// Layout: A chunks [BM*4] then B chunks [512]; chunk c -> sm + c*8 elems.
// Per wave: dst = base + lane*16B (linear) as required by HW.
// ---------------------------------------------------------------------------
template<int BM, typename T>
__device__ inline void stage_direct(const T* __restrict__ A, const T* __restrict__ Bt,
                                    int K, int k0, int row0, int col0, T* sm, int tid) {
    constexpr int CA = BM * 4;
    constexpr int TOT = CA + 512;
#pragma unroll
    for (int j = 0; j < TOT / 256; ++j) {
        int c = j * 256 + tid;
        bool isA = (c < CA);
        int cc = isA ? c : c - CA;
        int r = cc >> 2, kof = (cc & 3) * 8;
        int grow = isA ? (row0 + r) : (col0 + r);
        const T* src = (isA ? A : Bt) + (size_t)grow * K + k0 + kof;
        gload16(src, sm + c * 8);
    }
}

// ---------------------------------------------------------------------------
// Split-fp16 MFMA GEMM (fp32-accurate). Tile BM x 128, BK=32, 4 waves (2x2),
// mfma_f32_16x16x32_f16, 3 products per fragment pair.
// A planes [M,K] fp16 row-major, B planes [N,K] fp16 row-major (transposed).
// DUAL: N=1024 concat; cols<512 -> Cf(out stride cL)+Cb bf16; cols>=512 -> Cf2.
// ---------------------------------------------------------------------------
// EPI: 0=none, 1=relu. WF16: write post-epilogue hi/lo fp16 planes.
// OB16: write bf16 copy (non-DUAL). Cf (fp32) always written.
template<int BM, int EPI, bool WF16, bool OB16, bool DUAL>
__global__ __launch_bounds__(256)
void gemm_sp(const _Float16* __restrict__ Ah, const _Float16* __restrict__ Al,
             const _Float16* __restrict__ Bh, const _Float16* __restrict__ Bl,
             const float* __restrict__ bias, const float* __restrict__ bias2,
             float* __restrict__ Cf, bf16* __restrict__ Cb,
             _Float16* __restrict__ Ph, _Float16* __restrict__ Pl,
             float* __restrict__ Cf2, int N, int K) {
    constexpr int MT = BM / 32;
    constexpr int PL = (BM + 128) * 32;    // halves per plane
    __shared__ __align__(16) _Float16 sm[PL * 2];
    _Float16* smH = sm;
    _Float16* smL = sm + PL;
    const int tid = threadIdx.x;
    const int wid = tid >> 6, lane = tid & 63;
    const int wm = wid >> 1, wn = wid & 1;
    const int row0 = blockIdx.y * BM, col0 = blockIdx.x * 128;
    const int lr = lane & 15, lq = lane >> 4;

    f32x4 acc[MT][4];
#pragma unroll
    for (int mt = 0; mt < MT; ++mt)
#pragma unroll
        for (int nt = 0; nt < 4; ++nt)
            acc[mt][nt] = (f32x4){0.f, 0.f, 0.f, 0.f};

    for (int k0 = 0; k0 < K; k0 += 32) {
        stage_direct<BM, _Float16>(Ah, Bh, K, k0, row0, col0, smH, tid);
        stage_direct<BM, _Float16>(Al, Bl, K, k0, row0, col0, smL, tid);
        __syncthreads();
        half8 ah[MT], al8[MT], bh[4], bl[4];
#pragma unroll
        for (int mt = 0; mt < MT; ++mt) {
            int rit = wm * (BM / 2) + mt * 16 + lr;
            ah[mt]  = *(const half8*)(smH + rit * 32 + lq * 8);
            al8[mt] = *(const half8*)(smL + rit * 32 + lq * 8);
        }
#pragma unroll
        for (int nt = 0; nt < 4; ++nt) {
            int nit = wn * 64 + nt * 16 + lr;
            bh[nt] = *(const half8*)(smH + BM * 32 + nit * 32 + lq * 8);
            bl[nt] = *(const half8*)(smL + BM * 32 + nit * 32 + lq * 8);
        }
#pragma unroll
        for (int mt = 0; mt < MT; ++mt)
#pragma unroll
            for (int nt = 0; nt < 4; ++nt) {
                acc[mt][nt] = __builtin_amdgcn_mfma_f32_16x16x32_f16(
                    ah[mt], bh[nt], acc[mt][nt], 0, 0, 0);
                acc[mt][nt] = __builtin_amdgcn_mfma_f32_16x16x32_f16(
                    al8[mt], bh[nt], acc[mt][nt], 0, 0, 0);
                acc[mt][nt] = __builtin_amdgcn_mfma_f32_16x16x32_f16(
                    ah[mt], bl[nt], acc[mt][nt], 0, 0, 0);
            }
        __syncthreads();
    }

#pragma unroll
    for (int mt = 0; mt < MT; ++mt) {
#pragma unroll
        for (int nt = 0; nt < 4; ++nt) {
            int col = col0 + wn * 64 + nt * 16 + lr;
            float bv;
            if (DUAL) bv = (col < cL) ? bias[col] : bias2[col - cL];
            else      bv = bias[col];
#pragma unroll
            for (int r = 0; r < 4; ++r) {
                int row = row0 + wm * (BM / 2) + mt * 16 + lq * 4 + r;
                float z = acc[mt][nt][r] + bv;
                if (EPI == 1) z = fmaxf(z, 0.0f);
                if (DUAL) {
                    if (col < cL) {
                        size_t o = (size_t)row * cL + col;
                        Cf[o] = z;
                        Cb[o] = __float2bfloat16(z);
                    } else {
                        Cf2[(size_t)row * cL + (col - cL)] = z;
                    }
                } else {
                    size_t o = (size_t)row * N + col;
                    Cf[o] = z;
                    if (WF16) {
                        _Float16 hh = (_Float16)z;
                        Ph[o] = hh;
                        Pl[o] = (_Float16)(z - (float)hh);
                    }
                    if (OB16) Cb[o] = __float2bfloat16(z);
                }
            }
        }
    }
}

// ---------------------------------------------------------------------------
// bf16 MFMA GEMM core. Tile BM x 128, BK=32, 256 threads = 4 waves (2x2),
// wave tile (BM/2) x 64, mfma_f32_16x16x32_bf16.
// A is [M,K] row-major bf16, Bt is [N,K] row-major bf16 (B transposed).
// ---------------------------------------------------------------------------
// EPI: 0=none, 1=relu, 2=sigmoid, 3=(x+1)*0.5
template<int BM, int EPI, bool BIAS, bool RSC, bool OF32, bool OB16>
__global__ __launch_bounds__(256)
void gemm_bf(const void* __restrict__ A, const void* __restrict__ Bt,
             const float* __restrict__ bias, const float* __restrict__ rsc,
             float* __restrict__ Cf, bf16* __restrict__ Cb, int N, int K) {
    constexpr int MT = BM / 32;
    __shared__ __align__(16) bf16 sm[(BM + 128) * 32];
    bf16* smB = sm + BM * 32;
    const int tid = threadIdx.x;
    const int wid = tid >> 6, lane = tid & 63;
    const int wm = wid >> 1, wn = wid & 1;
    const int row0 = blockIdx.y * BM, col0 = blockIdx.x * 128;
    const int lr = lane & 15, lq = lane >> 4;

    f32x4 acc[MT][4];
#pragma unroll
    for (int mt = 0; mt < MT; ++mt)
#pragma unroll
        for (int nt = 0; nt < 4; ++nt)
            acc[mt][nt] = (f32x4){0.f, 0.f, 0.f, 0.f};

    for (int k0 = 0; k0 < K; k0 += 32) {
        stage_direct<BM, bf16>((const bf16*)A, (const bf16*)Bt, K, k0, row0, col0, sm, tid);
        __syncthreads();
        short8 af[MT], bfr[4];
#pragma unroll
        for (int mt = 0; mt < MT; ++mt) {
            int rit = wm * (BM / 2) + mt * 16 + lr;
            af[mt] = *(const short8*)(sm + rit * 32 + lq * 8);
        }
#pragma unroll
        for (int nt = 0; nt < 4; ++nt) {
            int nit = wn * 64 + nt * 16 + lr;
            bfr[nt] = *(const short8*)(smB + nit * 32 + lq * 8);
        }
#pragma unroll
        for (int mt = 0; mt < MT; ++mt)
#pragma unroll
            for (int nt = 0; nt < 4; ++nt)
                acc[mt][nt] = __builtin_amdgcn_mfma_f32_16x16x32_bf16(
                    af[mt], bfr[nt], acc[mt][nt], 0, 0, 0);
        __syncthreads();
    }

#pragma unroll
    for (int mt = 0; mt < MT; ++mt) {
#pragma unroll
        for (int nt = 0; nt < 4; ++nt) {
            int col = col0 + wn * 64 + nt * 16 + lr;
            float bv = BIAS ? bias[col] : 0.0f;
#pragma unroll
            for (int r = 0; r < 4; ++r) {
                int row = row0 + wm * (BM / 2) + mt * 16 + lq * 4 + r;
                float z = acc[mt][nt][r] + bv;
                if (EPI == 1) z = fmaxf(z, 0.0f);
                else if (EPI == 2) z = 1.0f / (1.0f + expf(-z));
                else if (EPI == 3) z = (z + 1.0f) * 0.5f;
                if (RSC) z *= rsc[row];
                if (OF32) Cf[(size_t)row * N + col] = z;
                if (OB16) Cb[(size_t)row * N + col] = __float2bfloat16(z);
            }
        }
    }
}

// ---------------------------------------------------------------------------
// Coarse distance GEMM (bf16 operands precomputed) with per-row per-64-col
// top-2 key output. d = cnorm[col] - 2 * (bbn . ctx_col).
// key = mono(d)<<32 | col. topbuf layout: [row][N/64][2] u64.
// ---------------------------------------------------------------------------
__global__ __launch_bounds__(256)
void gemm_dist(const bf16* __restrict__ A, const bf16* __restrict__ Bt,
               const float* __restrict__ cnorm, u64* __restrict__ topbuf,
               int N, int K) {
    constexpr int MT = 4;
    __shared__ __align__(16) bf16 sm[(128 + 128) * 32];
    bf16* smB = sm + 128 * 32;
    const int tid = threadIdx.x;
    const int wid = tid >> 6, lane = tid & 63;
    const int wm = wid >> 1, wn = wid & 1;
    const int row0 = blockIdx.y * 128, col0 = blockIdx.x * 128;
    const int lr = lane & 15, lq = lane >> 4;

    f32x4 acc[MT][4];
#pragma unroll
    for (int mt = 0; mt < MT; ++mt)
#pragma unroll
        for (int nt = 0; nt < 4; ++nt)
            acc[mt][nt] = (f32x4){0.f, 0.f, 0.f, 0.f};

    for (int k0 = 0; k0 < K; k0 += 32) {
        stage_direct<128, bf16>(A, Bt, K, k0, row0, col0, sm, tid);
        __syncthreads();
        short8 af[MT], bfr[4];
#pragma unroll
        for (int mt = 0; mt < MT; ++mt) {
            int rit = wm * 64 + mt * 16 + lr;
            af[mt] = *(const short8*)(sm + rit * 32 + lq * 8);
        }
#pragma unroll
        for (int nt = 0; nt < 4; ++nt) {
            int nit = wn * 64 + nt * 16 + lr;
            bfr[nt] = *(const short8*)(smB + nit * 32 + lq * 8);
        }
#pragma unroll
        for (int mt = 0; mt < MT; ++mt)
#pragma unroll
            for (int nt = 0; nt < 4; ++nt)
                acc[mt][nt] = __builtin_amdgcn_mfma_f32_16x16x32_bf16(
                    af[mt], bfr[nt], acc[mt][nt], 0, 0, 0);
        __syncthreads();
    }

    const int nhalves = N >> 6;
    const int half = blockIdx.x * 2 + wn;
    float cn[4];
#pragma unroll
    for (int nt = 0; nt < 4; ++nt)
        cn[nt] = cnorm[col0 + wn * 64 + nt * 16 + lr];

#pragma unroll
    for (int mt = 0; mt < 4; ++mt) {
#pragma unroll
        for (int r = 0; r < 4; ++r) {
            int row = row0 + wm * 64 + mt * 16 + lq * 4 + r;
            u64 k0v = ~0ull, k1v = ~0ull;
#pragma unroll
            for (int nt = 0; nt < 4; ++nt) {
                int col = col0 + wn * 64 + nt * 16 + lr;
                float d = cn[nt] - 2.0f * acc[mt][nt][r];
                u64 kk = ((u64)monoKey(d) << 32) | (u32)col;
                if (kk < k0v) { k1v = k0v; k0v = kk; }
                else if (kk < k1v) k1v = kk;
            }
#pragma unroll
            for (int m = 1; m <= 8; m <<= 1) {
                u64 o0 = shflxor_u64_w16(k0v, m);
                u64 o1 = shflxor_u64_w16(k1v, m);
                u64 n0 = k0v < o0 ? k0v : o0;
                u64 hi = k0v < o0 ? o0 : k0v;
                u64 lo2 = k1v < o1 ? k1v : o1;
                k0v = n0;
                k1v = hi < lo2 ? hi : lo2;
            }
            if (lr == 0) {
                u64* p = topbuf + ((size_t)row * nhalves + half) * 2;
                p[0] = k0v; p[1] = k1v;
            }
        }
    }
}

// Resolve: block per row. Find global coarse min over 256 candidate keys,
// exact-rescore (fp32) every candidate within MARGIN, atomicMin exact key.
__global__ __launch_bounds__(256)
void dist_resolve(const u64* __restrict__ topbuf, const float* __restrict__ bbn,
                  const float* __restrict__ ctx, const float* __restrict__ cnorm,
                  u64* __restrict__ argred) {
    int row = blockIdx.x, t = threadIdx.x;
    u64 my = topbuf[(size_t)row * 256 + t];
    __shared__ u64 red[256];
    red[t] = my;
    __syncthreads();
    for (int s = 128; s > 0; s >>= 1) {
        if (t < s) { u64 o = red[t + s]; if (o < red[t]) red[t] = o; }
        __syncthreads();
    }
    float bestd = keyToFloat((u32)(red[0] >> 32));
    float thr = bestd + MARGIN;
    float myd = keyToFloat((u32)(my >> 32));
    if (myd <= thr) {
        int idx = (int)(my & 0xFFFFFFFFu);
        const float4* b4 = (const float4*)(bbn + (size_t)row * cL);
        const float4* c4 = (const float4*)(ctx + (size_t)idx * cL);
        float s = 0.f;
        for (int i = 0; i < cL / 4; ++i) {
            float4 x = b4[i], y = c4[i];
            s = fmaf(x.x, y.x, s); s = fmaf(x.y, y.y, s);
            s = fmaf(x.z, y.z, s); s = fmaf(x.w, y.w, s);
        }
        float ex = cnorm[idx] - 2.0f * s;
        u64 k = ((u64)monoKey(ex) << 32) | (u32)idx;
        atomicMin(&argred[row], k);
    }
}

// ---------------------------------------------------------------------------
// Small helpers
// ---------------------------------------------------------------------------
// per-row sum of squares of ctx + bf16 copy. 64 threads/row, cols=512.
__global__ void rowsumsq_cvt(const float* __restrict__ Mx, float* __restrict__ outv,
                             bf16* __restrict__ outb) {
    int row = blockIdx.x, t = threadIdx.x;  // 64 threads
    const float4* p = (const float4*)(Mx + (size_t)row * cL);
    float4 v0 = p[2 * t], v1 = p[2 * t + 1];
    float s = v0.x * v0.x + v0.y * v0.y + v0.z * v0.z + v0.w * v0.w
            + v1.x * v1.x + v1.y * v1.y + v1.z * v1.z + v1.w * v1.w;
    union { short8 v; bf16 h[8]; } u;
    u.h[0] = __float2bfloat16(v0.x); u.h[1] = __float2bfloat16(v0.y);
    u.h[2] = __float2bfloat16(v0.z); u.h[3] = __float2bfloat16(v0.w);
    u.h[4] = __float2bfloat16(v1.x); u.h[5] = __float2bfloat16(v1.y);
    u.h[6] = __float2bfloat16(v1.z); u.h[7] = __float2bfloat16(v1.w);
    *(short8*)(outb + (size_t)row * cL + t * 8) = u.v;
    for (int off = 32; off >= 1; off >>= 1) s += __shfl_xor(s, off, 64);
    if (t == 0) outv[row] = s;
}

// transpose + fp32->bf16 convert (+ optional input-row scale): out[c][r] = in[r][c]*s[r]
__global__ __launch_bounds__(256)
void transpose_cvt(const float* __restrict__ in, bf16* __restrict__ out,
                   const float* __restrict__ scale, int R, int C) {
    __shared__ float tile[32][33];
    int c0 = blockIdx.x * 32, r0 = blockIdx.y * 32;
    int tx = threadIdx.x & 31, ty = threadIdx.x >> 5;
#pragma unroll
    for (int i = 0; i < 4; ++i) {
        int rr = ty + i * 8;
        int r = r0 + rr;
        float v = in[(size_t)r * C + c0 + tx];
        if (scale) v *= scale[r];
        tile[rr][tx] = v;
    }
    __syncthreads();
#pragma unroll
    for (int i = 0; i < 4; ++i) {
        int a = ty + i * 8;
        out[(size_t)(c0 + a) * R + r0 + tx] = __float2bfloat16(tile[tx][a]);
    }
}

// gather quantized code, normalize -> vnb (bf16); scatter one-hot
__global__ void gather_vn(const u64* __restrict__ argred, const float* __restrict__ ctx,
                          bf16* __restrict__ vnb, float* __restrict__ out_ci) {
    int row = blockIdx.x, t = threadIdx.x;  // 64 threads
    u32 idx = (u32)(argred[row] & 0xFFFFFFFFull);
    const float4* c4 = (const float4*)(ctx + (size_t)idx * cL);
    float4 v0 = c4[2 * t], v1 = c4[2 * t + 1];
    float s = v0.x * v0.x + v0.y * v0.y + v0.z * v0.z + v0.w * v0.w
            + v1.x * v1.x + v1.y * v1.y + v1.z * v1.z + v1.w * v1.w;
    for (int off = 32; off >= 1; off >>= 1) s += __shfl_xor(s, off, 64);
    float inv = rsqrtf(s + 1e-8f);
    union { short8 v; bf16 h[8]; } u;
    u.h[0] = __float2bfloat16(v0.x * inv); u.h[1] = __float2bfloat16(v0.y * inv);
    u.h[2] = __float2bfloat16(v0.z * inv); u.h[3] = __float2bfloat16(v0.w * inv);
    u.h[4] = __float2bfloat16(v1.x * inv); u.h[5] = __float2bfloat16(v1.y * inv);
    u.h[6] = __float2bfloat16(v1.z * inv); u.h[7] = __float2bfloat16(v1.w * inv);
    *(short8*)(vnb + (size_t)row * cL + t * 8) = u.v;
    if (t == 0) out_ci[(size_t)row * cK + idx] = 1.0f;
}

__global__ void colsum_b(const bf16* __restrict__ vnb, float* __restrict__ Svec) {
    int col = blockIdx.x * 256 + threadIdx.x;
    int r0 = blockIdx.y * 256;
    float s = 0.f;
    for (int r = r0; r < r0 + 256; ++r) s += __bfloat162float(vnb[(size_t)r * cL + col]);
    atomicAdd(&Svec[col], s);
}

__global__ void dinv_b(const bf16* __restrict__ vnb, const float* __restrict__ Svec,
                       float* __restrict__ dinv) {
    int row = blockIdx.x, t = threadIdx.x;  // 64 threads
    float s = 0.f;
#pragma unroll
    for (int i = 0; i < 8; ++i) {
        int c = t * 8 + i;
        s += __bfloat162float(vnb[(size_t)row * cL + c]) * Svec[c];
    }
    for (int off = 32; off >= 1; off >>= 1) s += __shfl_xor(s, off, 64);
    if (t == 0) dinv[row] = rsqrtf(0.5f * (s + (float)cB) + 1e-8f);
}

// ---------------------------------------------------------------------------
extern "C" void kernel_launch(void* const* d_in, const int* in_sizes, int n_in,
                              void* d_out, int out_size, void* d_ws, size_t ws_size,
                              hipStream_t stream) {
    const float* x      = (const float*)d_in[0];
    const float* W_enc  = (const float*)d_in[1];
    const float* b_enc  = (const float*)d_in[2];
    const float* W_fc1  = (const float*)d_in[3];
    const float* b_fc1  = (const float*)d_in[4];
    const float* W_fc2  = (const float*)d_in[5];
    const float* b_fc2  = (const float*)d_in[6];
    const float* ctx    = (const float*)d_in[7];
    const float* W_gcn  = (const float*)d_in[8];
    const float* b_gcn  = (const float*)d_in[9];
    const float* W_dec1 = (const float*)d_in[10];
    const float* b_dec1 = (const float*)d_in[11];
    const float* W_dec2 = (const float*)d_in[12];
    const float* b_dec2 = (const float*)d_in[13];

    float* out = (float*)d_out;
    float* out_dec  = out;                                   // [B,F]
    float* out_bbn  = out_dec + (size_t)cB * cF;             // [B,L]
    float* out_ci   = out_bbn + (size_t)cB * cL;             // [B,K]
    float* out_feat = out_ci  + (size_t)cB * cK;             // [B,H]
    float* out_adj  = out_feat + (size_t)cB * cH;            // [B,B]

    char* p = (char*)d_ws;
    auto alloc = [&](size_t n) { void* r = p; p += (n + 255) & ~(size_t)255; return r; };
    float* cnorm  = (float*)alloc((size_t)cK * 4);
    float* Svec   = (float*)alloc((size_t)cL * 4);
    float* dinvp  = (float*)alloc((size_t)cB * 4);
    u64* argred   = (u64*)alloc((size_t)cB * 8);
    u64* topbuf   = (u64*)alloc((size_t)cB * 256 * 8);        // [B][128][2]
    bf16* W_gcnt  = (bf16*)alloc((size_t)cL * cL * 2);
    bf16* W_dec1t = (bf16*)alloc((size_t)cH * cL * 2);
    bf16* W_dec2t = (bf16*)alloc((size_t)cF * cH * 2);
    bf16* vnb     = (bf16*)alloc((size_t)cB * cL * 2);
    float* cbn    = (float*)alloc((size_t)cB * cL * 4);
    bf16* cbnst   = (bf16*)alloc((size_t)cL * cB * 2);        // [L][B]
    bf16* tbufb   = (bf16*)alloc((size_t)cB * cL * 2);
    bf16* latentb = (bf16*)alloc((size_t)cB * cL * 2);
    bf16* h1b     = (bf16*)alloc((size_t)cB * cH * 2);
    bf16* adjb    = (bf16*)alloc((size_t)cB * cB * 2);        // bf16 adj copy
    // split-fp16 planes for the fp32-accurate chain
    _Float16* xh     = (_Float16*)alloc((size_t)cB * cF * 2);
    _Float16* xl     = (_Float16*)alloc((size_t)cB * cF * 2);
    _Float16* wet_h  = (_Float16*)alloc((size_t)cH * cF * 2); // W_enc^T planes [H,F]
    _Float16* wet_l  = (_Float16*)alloc((size_t)cH * cF * 2);
    _Float16* feat_h = (_Float16*)alloc((size_t)cB * cH * 2);
    _Float16* feat_l = (_Float16*)alloc((size_t)cB * cH * 2);
    _Float16* wf12t_h = (_Float16*)alloc((size_t)cH * cH * 2); // [W_fc1|W_fc2]^T planes [1024,H]
    _Float16* wf12t_l = (_Float16*)alloc((size_t)cH * cH * 2);
    bf16* bbnb       = (bf16*)alloc((size_t)cB * cL * 2);
    bf16* ctxb       = (bf16*)alloc((size_t)cK * cL * 2);

    dim3 blk(256);

    hipMemsetAsync(out_ci, 0, (size_t)cB * cK * sizeof(float), stream);
    hipMemsetAsync(argred, 0xFF, (size_t)cB * sizeof(u64), stream);
    hipMemsetAsync(Svec, 0, cL * sizeof(float), stream);

    // ---- split operands for fp32-accurate fp16-MFMA chain ----
    split_f16<<<(cB * (size_t)cF) / 2048, blk, 0, stream>>>(x, xh, xl);
    transpose_split<<<dim3(cH / 32, cF / 32), blk, 0, stream>>>(W_enc, wet_h, wet_l, cF, cH);
    // concat [W_fc1 | W_fc2]^T into rows 0-511 / 512-1023 of wf12t planes
    transpose_split<<<dim3(cL / 32, cH / 32), blk, 0, stream>>>(
        W_fc1, wf12t_h, wf12t_l, cH, cL);
    transpose_split<<<dim3(cL / 32, cH / 32), blk, 0, stream>>>(
        W_fc2, wf12t_h + (size_t)cL * cH, wf12t_l + (size_t)cL * cH, cH, cL);

    // ---- feat = relu(x @ W_enc + b_enc)  [fp32-accurate split GEMM, 128-tile] ----
    gemm_sp<128, 1, true, false, false><<<dim3(cH / 128, cB / 128), blk, 0, stream>>>(
        xh, xl, wet_h, wet_l, b_enc, nullptr, out_feat, nullptr, feat_h, feat_l,
        nullptr, cH, cF);

    // ---- [bbn | cbn] = feat @ [W_fc1|W_fc2] + [b_fc1|b_fc2]  [dual split GEMM] ----
    gemm_sp<128, 0, false, true, true><<<dim3(cH / 128, cB / 128), blk, 0, stream>>>(
        feat_h, feat_l, wf12t_h, wf12t_l, b_fc1, b_fc2, out_bbn, bbnb,
        nullptr, nullptr, cbn, cH, cH);

    // ---- prep: codebook norms + bf16 copy, weight transposes ----
    rowsumsq_cvt<<<cK, 64, 0, stream>>>(ctx, cnorm, ctxb);
    transpose_cvt<<<dim3(cL / 32, cL / 32), blk, 0, stream>>>(W_gcn, W_gcnt, nullptr, cL, cL);
    transpose_cvt<<<dim3(cH / 32, cL / 32), blk, 0, stream>>>(W_dec1, W_dec1t, nullptr, cL, cH);
    transpose_cvt<<<dim3(cF / 32, cH / 32), blk, 0, stream>>>(W_dec2, W_dec2t, nullptr, cH, cF);

    // ---- coarse distances (bf16 MFMA) + exact argmin resolve ----
    gemm_dist<<<dim3(cK / 128, cB / 128), blk, 0, stream>>>(bbnb, ctxb, cnorm, topbuf, cK, cL);
    dist_resolve<<<cB, blk, 0, stream>>>(topbuf, out_bbn, ctx, cnorm, argred);

    // ---- quantize / normalize / one-hot ----
    gather_vn<<<cB, 64, 0, stream>>>(argred, ctx, vnb, out_ci);
    colsum_b<<<dim3(cL / 256, cB / 256), blk, 0, stream>>>(vnb, Svec);
    dinv_b<<<cB, 64, 0, stream>>>(vnb, Svec, dinvp);

    // ---- adj = (vn @ vn^T + 1) * 0.5  (+ bf16 copy for GCN GEMM) ----
    gemm_bf<128, 3, false, false, true, true>
        <<<dim3(cB / 128, cB / 128), blk, 0, stream>>>(vnb, vnb, nullptr, nullptr, out_adj, adjb, cB, cL);

    // ---- cbnst[l][j] = dinv[j] * cbn[j][l] (bf16 transposed) ----
    transpose_cvt<<<dim3(cL / 32, cB / 32), blk, 0, stream>>>(cbn, cbnst, dinvp, cB, cL);

    // ---- t = dinv[i] * (adj @ cbn_scaled)  (bf16 adj copy) ----
    gemm_bf<64, 0, false, true, false, true>
        <<<dim3(cL / 128, cB / 64), blk, 0, stream>>>(adjb, cbnst, nullptr, dinvp, nullptr, tbufb, cL, cB);

    // ---- latent = sigmoid(t @ W_gcn + b_gcn) ----
    gemm_bf<64, 2, true, false, false, true>
        <<<dim3(cL / 128, cB / 64), blk, 0, stream>>>(tbufb, W_gcnt, b_gcn, nullptr, nullptr, latentb, cL, cL);

    // ---- h1 = relu(latent @ W_dec1 + b_dec1) ----
    gemm_bf<128, 1, true, false, false, true>
        <<<dim3(cH / 128, cB / 128), blk, 0, stream>>>(latentb, W_dec1t, b_dec1, nullptr, nullptr, h1b, cH, cL);

    // ---- decoded = h1 @ W_dec2 + b_dec2 ----
    gemm_bf<128, 0, true, false, true, false>
        <<<dim3(cF / 128, cB / 128), blk, 0, stream>>>(h1b, W_dec2t, b_dec2, nullptr, out_dec, nullptr, cF, cH);
}

// Round 4
// 840.584 us; speedup vs baseline: 1.1146x; 1.1146x over previous
//
#include <hip/hip_runtime.h>
#include <hip/hip_bf16.h>
#include <stdint.h>

using u32 = unsigned int;
using u64 = unsigned long long;
using bf16 = __hip_bfloat16;
typedef __attribute__((ext_vector_type(8))) short short8;
typedef __attribute__((ext_vector_type(4))) float f32x4;
typedef __attribute__((ext_vector_type(8))) _Float16 half8;

constexpr int cB = 4096;   // batch
constexpr int cF = 4096;   // feat dim
constexpr int cH = 1024;   // enc hidden
constexpr int cL = 512;    // latent
constexpr int cK = 8192;   // codebook size
constexpr float MARGIN = 0.02f;  // >> max coarse bf16 distance error (~2.5e-3)

// monotone float->u32 key (ascending order preserved)
__device__ inline u32 monoKey(float d) {
    u32 u = __float_as_uint(d);
    return (u & 0x80000000u) ? ~u : (u | 0x80000000u);
}
__device__ inline float keyToFloat(u32 k) {
    u32 u = (k & 0x80000000u) ? (k ^ 0x80000000u) : ~k;
    return __uint_as_float(u);
}

__device__ inline u64 shflxor_u64_w16(u64 v, int mask) {
    u32 lo = (u32)v, hi = (u32)(v >> 32);
    lo = (u32)__shfl_xor((int)lo, mask, 16);
    hi = (u32)__shfl_xor((int)hi, mask, 16);
    return ((u64)hi << 32) | lo;
}

// async global->LDS, 16B per lane. LDS dest must be linear in lane order
// (wave-uniform base + lane*16) -- our staging layout satisfies this.
__device__ inline void gload16(const void* g, void* s) {
    __builtin_amdgcn_global_load_lds(
        (__attribute__((address_space(1))) void*)(void*)g,
        (__attribute__((address_space(3))) void*)s, 16, 0, 0);
}

// ---------------------------------------------------------------------------
// fp32-via-fp16 split helpers: x = hi + lo, hi=fp16(x), lo=fp16(x-hi).
// hi*hi' + lo*hi' + hi*lo' reproduces x*x' to ~2^-22 relative (fp32-level).
// ---------------------------------------------------------------------------

// elementwise split: in fp32 [n] -> hi/lo fp16 planes. 8 elts/thread.
__global__ __launch_bounds__(256)
void split_f16(const float* __restrict__ in, _Float16* __restrict__ hi,
               _Float16* __restrict__ lo) {
    size_t base = ((size_t)blockIdx.x * 256 + threadIdx.x) * 8;
    float4 a = *(const float4*)(in + base);
    float4 b = *(const float4*)(in + base + 4);
    float v[8] = {a.x, a.y, a.z, a.w, b.x, b.y, b.z, b.w};
    half8 h, l;
#pragma unroll
    for (int i = 0; i < 8; ++i) {
        _Float16 hh = (_Float16)v[i];
        h[i] = hh;
        l[i] = (_Float16)(v[i] - (float)hh);
    }
    *(half8*)(hi + base) = h;
    *(half8*)(lo + base) = l;
}

// transpose + split: oh/ol[c][r] = split(in[r][c])
__global__ __launch_bounds__(256)
void transpose_split(const float* __restrict__ in, _Float16* __restrict__ oh,
                     _Float16* __restrict__ ol, int R, int C) {
    __shared__ float tile[32][33];
    int c0 = blockIdx.x * 32, r0 = blockIdx.y * 32;
    int tx = threadIdx.x & 31, ty = threadIdx.x >> 5;
#pragma unroll
    for (int i = 0; i < 4; ++i) {
        int rr = ty + i * 8;
        tile[rr][tx] = in[(size_t)(r0 + rr) * C + c0 + tx];
    }
    __syncthreads();
#pragma unroll
    for (int i = 0; i < 4; ++i) {
        int a = ty + i * 8;
        float v = tile[tx][a];
        _Float16 hh = (_Float16)v;
        size_t o = (size_t)(c0 + a) * R + r0 + tx;
        oh[o] = hh;
        ol[o] = (_Float16)(v - (float)hh);
    }
}

// ---------------------------------------------------------------------------
// Staging via global_load_lds, width 16B, BK=64 (8 x 16B slots per row).
// Slot-XOR swizzle (slot ^= row&7) applied to the GLOBAL source address;
// LDS dest stays linear per-lane (HW requirement). Reads apply the same
// involution, spreading the 128B-row b128 reads across all bank quads.
// Layout: A rows [BM][64] then B rows [128][64]; chunk c -> sm + c*8 elems.
// ---------------------------------------------------------------------------
template<int BM, typename T>
__device__ inline void stage_direct(const T* __restrict__ A, const T* __restrict__ Bt,
                                    int K, int k0, int row0, int col0, T* sm, int tid) {
    constexpr int CA = BM * 8;
    constexpr int TOT = CA + 1024;
#pragma unroll
    for (int j = 0; j < TOT / 256; ++j) {
        int c = j * 256 + tid;
        bool isA = (c < CA);
        int cc = isA ? c : c - CA;
        int r = cc >> 3, slot = cc & 7;
        int kof = (slot ^ (r & 7)) * 8;
        int grow = isA ? (row0 + r) : (col0 + r);
        const T* src = (isA ? A : Bt) + (size_t)grow * K + k0 + kof;
        gload16(src, sm + c * 8);
    }
}

// swizzled fragment address within a [rows][64] LDS tile
template<typename T>
__device__ inline const short8* frag8(const T* smb, int row, int s) {
    return (const short8*)((const bf16*)smb + row * 64 + ((s ^ (row & 7)) * 8));
}

// ---------------------------------------------------------------------------
// Split-fp16 MFMA GEMM (fp32-accurate). Tile BM x 128, BK=64, 4 waves (2x2),
// mfma_f32_16x16x32_f16, 3 products per fragment pair.
// A planes [M,K] fp16 row-major, B planes [N,K] fp16 row-major (transposed).
// DUAL: N=1024 concat; cols<512 -> Cf(out stride cL)+Cb bf16; cols>=512 -> Cf2.
// ---------------------------------------------------------------------------
// EPI: 0=none, 1=relu. WF16: write post-epilogue hi/lo fp16 planes.
template<int BM, int EPI, bool WF16, bool DUAL>
__global__ __launch_bounds__(256)
void gemm_sp(const _Float16* __restrict__ Ah, const _Float16* __restrict__ Al,
             const _Float16* __restrict__ Bh, const _Float16* __restrict__ Bl,
             const float* __restrict__ bias, const float* __restrict__ bias2,
             float* __restrict__ Cf, bf16* __restrict__ Cb,
             _Float16* __restrict__ Ph, _Float16* __restrict__ Pl,
             float* __restrict__ Cf2, int N, int K) {
    constexpr int MT = BM / 32;
    constexpr int PL = (BM + 128) * 64;    // halves per plane
    __shared__ __align__(16) _Float16 sm[PL * 2];
    _Float16* smH = sm;
    _Float16* smL = sm + PL;
    const int tid = threadIdx.x;
    const int wid = tid >> 6, lane = tid & 63;
    const int wm = wid >> 1, wn = wid & 1;
    const int row0 = blockIdx.y * BM, col0 = blockIdx.x * 128;
    const int lr = lane & 15, lq = lane >> 4;

    f32x4 acc[MT][4];
#pragma unroll
    for (int mt = 0; mt < MT; ++mt)
#pragma unroll
        for (int nt = 0; nt < 4; ++nt)
            acc[mt][nt] = (f32x4){0.f, 0.f, 0.f, 0.f};

    for (int k0 = 0; k0 < K; k0 += 64) {
        stage_direct<BM, _Float16>(Ah, Bh, K, k0, row0, col0, smH, tid);
        stage_direct<BM, _Float16>(Al, Bl, K, k0, row0, col0, smL, tid);
        __syncthreads();
#pragma unroll
        for (int kk = 0; kk < 2; ++kk) {
            const int s = kk * 4 + lq;
            half8 ah[MT], al8[MT], bh[4], bl[4];
#pragma unroll
            for (int mt = 0; mt < MT; ++mt) {
                int rit = wm * (BM / 2) + mt * 16 + lr;
                ah[mt]  = *(const half8*)frag8(smH, rit, s);
                al8[mt] = *(const half8*)frag8(smL, rit, s);
            }
#pragma unroll
            for (int nt = 0; nt < 4; ++nt) {
                int nit = wn * 64 + nt * 16 + lr;
                bh[nt] = *(const half8*)frag8(smH + BM * 64, nit, s);
                bl[nt] = *(const half8*)frag8(smL + BM * 64, nit, s);
            }
#pragma unroll
            for (int mt = 0; mt < MT; ++mt)
#pragma unroll
                for (int nt = 0; nt < 4; ++nt) {
                    acc[mt][nt] = __builtin_amdgcn_mfma_f32_16x16x32_f16(
                        ah[mt], bh[nt], acc[mt][nt], 0, 0, 0);
                    acc[mt][nt] = __builtin_amdgcn_mfma_f32_16x16x32_f16(
                        al8[mt], bh[nt], acc[mt][nt], 0, 0, 0);
                    acc[mt][nt] = __builtin_amdgcn_mfma_f32_16x16x32_f16(
                        ah[mt], bl[nt], acc[mt][nt], 0, 0, 0);
                }
        }
        __syncthreads();
    }

#pragma unroll
    for (int mt = 0; mt < MT; ++mt) {
#pragma unroll
        for (int nt = 0; nt < 4; ++nt) {
            int col = col0 + wn * 64 + nt * 16 + lr;
            float bv;
            if (DUAL) bv = (col < cL) ? bias[col] : bias2[col - cL];
            else      bv = bias[col];
#pragma unroll
            for (int r = 0; r < 4; ++r) {
                int row = row0 + wm * (BM / 2) + mt * 16 + lq * 4 + r;
                float z = acc[mt][nt][r] + bv;
                if (EPI == 1) z = fmaxf(z, 0.0f);
                if (DUAL) {
                    if (col < cL) {
                        size_t o = (size_t)row * cL + col;
                        Cf[o] = z;
                        Cb[o] = __float2bfloat16(z);
                    } else {
                        Cf2[(size_t)row * cL + (col - cL)] = z;
                    }
                } else {
                    size_t o = (size_t)row * N + col;
                    Cf[o] = z;
                    if (WF16) {
                        _Float16 hh = (_Float16)z;
                        Ph[o] = hh;
                        Pl[o] = (_Float16)(z - (float)hh);
                    }
                }
            }
        }
    }
}

// ---------------------------------------------------------------------------
// bf16 MFMA GEMM core. Tile BM x 128, BK=64, 256 threads = 4 waves (2x2),
// wave tile (BM/2) x 64, mfma_f32_16x16x32_bf16.
// A is [M,K] row-major bf16, Bt is [N,K] row-major bf16 (B transposed).
// ---------------------------------------------------------------------------
// EPI: 0=none, 1=relu, 2=sigmoid, 3=(x+1)*0.5
template<int BM, int EPI, bool BIAS, bool RSC, bool OF32, bool OB16>
__global__ __launch_bounds__(256)
void gemm_bf(const void* __restrict__ A, const void* __restrict__ Bt,
             const float* __restrict__ bias, const float* __restrict__ rsc,
             float* __restrict__ Cf, bf16* __restrict__ Cb, int N, int K) {
    constexpr int MT = BM / 32;
    __shared__ __align__(16) bf16 sm[(BM + 128) * 64];
    bf16* smB = sm + BM * 64;
    const int tid = threadIdx.x;
    const int wid = tid >> 6, lane = tid & 63;
    const int wm = wid >> 1, wn = wid & 1;
    const int row0 = blockIdx.y * BM, col0 = blockIdx.x * 128;
    const int lr = lane & 15, lq = lane >> 4;

    f32x4 acc[MT][4];
#pragma unroll
    for (int mt = 0; mt < MT; ++mt)
#pragma unroll
        for (int nt = 0; nt < 4; ++nt)
            acc[mt][nt] = (f32x4){0.f, 0.f, 0.f, 0.f};

    for (int k0 = 0; k0 < K; k0 += 64) {
        stage_direct<BM, bf16>((const bf16*)A, (const bf16*)Bt, K, k0, row0, col0, sm, tid);
        __syncthreads();
#pragma unroll
        for (int kk = 0; kk < 2; ++kk) {
            const int s = kk * 4 + lq;
            short8 af[MT], bfr[4];
#pragma unroll
            for (int mt = 0; mt < MT; ++mt) {
                int rit = wm * (BM / 2) + mt * 16 + lr;
                af[mt] = *frag8(sm, rit, s);
            }
#pragma unroll
            for (int nt = 0; nt < 4; ++nt) {
                int nit = wn * 64 + nt * 16 + lr;
                bfr[nt] = *frag8(smB, nit, s);
            }
#pragma unroll
            for (int mt = 0; mt < MT; ++mt)
#pragma unroll
                for (int nt = 0; nt < 4; ++nt)
                    acc[mt][nt] = __builtin_amdgcn_mfma_f32_16x16x32_bf16(
                        af[mt], bfr[nt], acc[mt][nt], 0, 0, 0);
        }
        __syncthreads();
    }

#pragma unroll
    for (int mt = 0; mt < MT; ++mt) {
#pragma unroll
        for (int nt = 0; nt < 4; ++nt) {
            int col = col0 + wn * 64 + nt * 16 + lr;
            float bv = BIAS ? bias[col] : 0.0f;
#pragma unroll
            for (int r = 0; r < 4; ++r) {
                int row = row0 + wm * (BM / 2) + mt * 16 + lq * 4 + r;
                float z = acc[mt][nt][r] + bv;
                if (EPI == 1) z = fmaxf(z, 0.0f);
                else if (EPI == 2) z = 1.0f / (1.0f + expf(-z));
                else if (EPI == 3) z = (z + 1.0f) * 0.5f;
                if (RSC) z *= rsc[row];
                if (OF32) Cf[(size_t)row * N + col] = z;
                if (OB16) Cb[(size_t)row * N + col] = __float2bfloat16(z);
            }
        }
    }
}

// ---------------------------------------------------------------------------
// Coarse distance GEMM (bf16 operands precomputed) with per-row per-64-col
// top-2 key output. d = cnorm[col] - 2 * (bbn . ctx_col).
// key = mono(d)<<32 | col. topbuf layout: [row][N/64][2] u64.
// ---------------------------------------------------------------------------
__global__ __launch_bounds__(256)
void gemm_dist(const bf16* __restrict__ A, const bf16* __restrict__ Bt,
               const float* __restrict__ cnorm, u64* __restrict__ topbuf,
               int N, int K) {
    constexpr int MT = 4;
    __shared__ __align__(16) bf16 sm[(128 + 128) * 64];
    bf16* smB = sm + 128 * 64;
    const int tid = threadIdx.x;
    const int wid = tid >> 6, lane = tid & 63;
    const int wm = wid >> 1, wn = wid & 1;
    const int row0 = blockIdx.y * 128, col0 = blockIdx.x * 128;
    const int lr = lane & 15, lq = lane >> 4;

    f32x4 acc[MT][4];
#pragma unroll
    for (int mt = 0; mt < MT; ++mt)
#pragma unroll
        for (int nt = 0; nt < 4; ++nt)
            acc[mt][nt] = (f32x4){0.f, 0.f, 0.f, 0.f};

    for (int k0 = 0; k0 < K; k0 += 64) {
        stage_direct<128, bf16>(A, Bt, K, k0, row0, col0, sm, tid);
        __syncthreads();
#pragma unroll
        for (int kk = 0; kk < 2; ++kk) {
            const int s = kk * 4 + lq;
            short8 af[MT], bfr[4];
#pragma unroll
            for (int mt = 0; mt < MT; ++mt) {
                int rit = wm * 64 + mt * 16 + lr;
                af[mt] = *frag8(sm, rit, s);
            }
#pragma unroll
            for (int nt = 0; nt < 4; ++nt) {
                int nit = wn * 64 + nt * 16 + lr;
                bfr[nt] = *frag8(smB, nit, s);
            }
#pragma unroll
            for (int mt = 0; mt < MT; ++mt)
#pragma unroll
                for (int nt = 0; nt < 4; ++nt)
                    acc[mt][nt] = __builtin_amdgcn_mfma_f32_16x16x32_bf16(
                        af[mt], bfr[nt], acc[mt][nt], 0, 0, 0);
        }
        __syncthreads();
    }

    const int nhalves = N >> 6;
    const int half = blockIdx.x * 2 + wn;
    float cn[4];
#pragma unroll
    for (int nt = 0; nt < 4; ++nt)
        cn[nt] = cnorm[col0 + wn * 64 + nt * 16 + lr];

#pragma unroll
    for (int mt = 0; mt < 4; ++mt) {
#pragma unroll
        for (int r = 0; r < 4; ++r) {
            int row = row0 + wm * 64 + mt * 16 + lq * 4 + r;
            u64 k0v = ~0ull, k1v = ~0ull;
#pragma unroll
            for (int nt = 0; nt < 4; ++nt) {
                int col = col0 + wn * 64 + nt * 16 + lr;
                float d = cn[nt] - 2.0f * acc[mt][nt][r];
                u64 kk = ((u64)monoKey(d) << 32) | (u32)col;
                if (kk < k0v) { k1v = k0v; k0v = kk; }
                else if (kk < k1v) k1v = kk;
            }
#pragma unroll
            for (int m = 1; m <= 8; m <<= 1) {
                u64 o0 = shflxor_u64_w16(k0v, m);
                u64 o1 = shflxor_u64_w16(k1v, m);
                u64 n0 = k0v < o0 ? k0v : o0;
                u64 hi = k0v < o0 ? o0 : k0v;
                u64 lo2 = k1v < o1 ? k1v : o1;
                k0v = n0;
                k1v = hi < lo2 ? hi : lo2;
            }
            if (lr == 0) {
                u64* p = topbuf + ((size_t)row * nhalves + half) * 2;
                p[0] = k0v; p[1] = k1v;
            }
        }
    }
}

// Resolve: block per row. Find global coarse min over 256 candidate keys,
// exact-rescore (fp32) every candidate within MARGIN, atomicMin exact key.
__global__ __launch_bounds__(256)
void dist_resolve(const u64* __restrict__ topbuf, const float* __restrict__ bbn,
                  const float* __restrict__ ctx, const float* __restrict__ cnorm,
                  u64* __restrict__ argred) {
    int row = blockIdx.x, t = threadIdx.x;
    u64 my = topbuf[(size_t)row * 256 + t];
    __shared__ u64 red[256];
    red[t] = my;
    __syncthreads();
    for (int s = 128; s > 0; s >>= 1) {
        if (t < s) { u64 o = red[t + s]; if (o < red[t]) red[t] = o; }
        __syncthreads();
    }
    float bestd = keyToFloat((u32)(red[0] >> 32));
    float thr = bestd + MARGIN;
    float myd = keyToFloat((u32)(my >> 32));
    if (myd <= thr) {
        int idx = (int)(my & 0xFFFFFFFFu);
        const float4* b4 = (const float4*)(bbn + (size_t)row * cL);
        const float4* c4 = (const float4*)(ctx + (size_t)idx * cL);
        float s = 0.f;
        for (int i = 0; i < cL / 4; ++i) {
            float4 x = b4[i], y = c4[i];
            s = fmaf(x.x, y.x, s); s = fmaf(x.y, y.y, s);
            s = fmaf(x.z, y.z, s); s = fmaf(x.w, y.w, s);
        }
        float ex = cnorm[idx] - 2.0f * s;
        u64 k = ((u64)monoKey(ex) << 32) | (u32)idx;
        atomicMin(&argred[row], k);
    }
}

// ---------------------------------------------------------------------------
// Small helpers
// ---------------------------------------------------------------------------
// per-row sum of squares of ctx + bf16 copy. 64 threads/row, cols=512.
__global__ void rowsumsq_cvt(const float* __restrict__ Mx, float* __restrict__ outv,
                             bf16* __restrict__ outb) {
    int row = blockIdx.x, t = threadIdx.x;  // 64 threads
    const float4* p = (const float4*)(Mx + (size_t)row * cL);
    float4 v0 = p[2 * t], v1 = p[2 * t + 1];
    float s = v0.x * v0.x + v0.y * v0.y + v0.z * v0.z + v0.w * v0.w
            + v1.x * v1.x + v1.y * v1.y + v1.z * v1.z + v1.w * v1.w;
    union { short8 v; bf16 h[8]; } u;
    u.h[0] = __float2bfloat16(v0.x); u.h[1] = __float2bfloat16(v0.y);
    u.h[2] = __float2bfloat16(v0.z); u.h[3] = __float2bfloat16(v0.w);
    u.h[4] = __float2bfloat16(v1.x); u.h[5] = __float2bfloat16(v1.y);
    u.h[6] = __float2bfloat16(v1.z); u.h[7] = __float2bfloat16(v1.w);
    *(short8*)(outb + (size_t)row * cL + t * 8) = u.v;
    for (int off = 32; off >= 1; off >>= 1) s += __shfl_xor(s, off, 64);
    if (t == 0) outv[row] = s;
}

// transpose + fp32->bf16 convert (+ optional input-row scale): out[c][r] = in[r][c]*s[r]
__global__ __launch_bounds__(256)
void transpose_cvt(const float* __restrict__ in, bf16* __restrict__ out,
                   const float* __restrict__ scale, int R, int C) {
    __shared__ float tile[32][33];
    int c0 = blockIdx.x * 32, r0 = blockIdx.y * 32;
    int tx = threadIdx.x & 31, ty = threadIdx.x >> 5;
#pragma unroll
    for (int i = 0; i < 4; ++i) {
        int rr = ty + i * 8;
        int r = r0 + rr;
        float v = in[(size_t)r * C + c0 + tx];
        if (scale) v *= scale[r];
        tile[rr][tx] = v;
    }
    __syncthreads();
#pragma unroll
    for (int i = 0; i < 4; ++i) {
        int a = ty + i * 8;
        out[(size_t)(c0 + a) * R + r0 + tx] = __float2bfloat16(tile[tx][a]);
    }
}

// gather quantized code, normalize -> vnb (bf16); scatter one-hot
__global__ void gather_vn(const u64* __restrict__ argred, const float* __restrict__ ctx,
                          bf16* __restrict__ vnb, float* __restrict__ out_ci) {
    int row = blockIdx.x, t = threadIdx.x;  // 64 threads
    u32 idx = (u32)(argred[row] & 0xFFFFFFFFull);
    const float4* c4 = (const float4*)(ctx + (size_t)idx * cL);
    float4 v0 = c4[2 * t], v1 = c4[2 * t + 1];
    float s = v0.x * v0.x + v0.y * v0.y + v0.z * v0.z + v0.w * v0.w
            + v1.x * v1.x + v1.y * v1.y + v1.z * v1.z + v1.w * v1.w;
    for (int off = 32; off >= 1; off >>= 1) s += __shfl_xor(s, off, 64);
    float inv = rsqrtf(s + 1e-8f);
    union { short8 v; bf16 h[8]; } u;
    u.h[0] = __float2bfloat16(v0.x * inv); u.h[1] = __float2bfloat16(v0.y * inv);
    u.h[2] = __float2bfloat16(v0.z * inv); u.h[3] = __float2bfloat16(v0.w * inv);
    u.h[4] = __float2bfloat16(v1.x * inv); u.h[5] = __float2bfloat16(v1.y * inv);
    u.h[6] = __float2bfloat16(v1.z * inv); u.h[7] = __float2bfloat16(v1.w * inv);
    *(short8*)(vnb + (size_t)row * cL + t * 8) = u.v;
    if (t == 0) out_ci[(size_t)row * cK + idx] = 1.0f;
}

__global__ void colsum_b(const bf16* __restrict__ vnb, float* __restrict__ Svec) {
    int col = blockIdx.x * 256 + threadIdx.x;
    int r0 = blockIdx.y * 256;
    float s = 0.f;
    for (int r = r0; r < r0 + 256; ++r) s += __bfloat162float(vnb[(size_t)r * cL + col]);
    atomicAdd(&Svec[col], s);
}

__global__ void dinv_b(const bf16* __restrict__ vnb, const float* __restrict__ Svec,
                       float* __restrict__ dinv) {
    int row = blockIdx.x, t = threadIdx.x;  // 64 threads
    float s = 0.f;
#pragma unroll
    for (int i = 0; i < 8; ++i) {
        int c = t * 8 + i;
        s += __bfloat162float(vnb[(size_t)row * cL + c]) * Svec[c];
    }
    for (int off = 32; off >= 1; off >>= 1) s += __shfl_xor(s, off, 64);
    if (t == 0) dinv[row] = rsqrtf(0.5f * (s + (float)cB) + 1e-8f);
}

// ---------------------------------------------------------------------------
extern "C" void kernel_launch(void* const* d_in, const int* in_sizes, int n_in,
                              void* d_out, int out_size, void* d_ws, size_t ws_size,
                              hipStream_t stream) {
    const float* x      = (const float*)d_in[0];
    const float* W_enc  = (const float*)d_in[1];
    const float* b_enc  = (const float*)d_in[2];
    const float* W_fc1  = (const float*)d_in[3];
    const float* b_fc1  = (const float*)d_in[4];
    const float* W_fc2  = (const float*)d_in[5];
    const float* b_fc2  = (const float*)d_in[6];
    const float* ctx    = (const float*)d_in[7];
    const float* W_gcn  = (const float*)d_in[8];
    const float* b_gcn  = (const float*)d_in[9];
    const float* W_dec1 = (const float*)d_in[10];
    const float* b_dec1 = (const float*)d_in[11];
    const float* W_dec2 = (const float*)d_in[12];
    const float* b_dec2 = (const float*)d_in[13];

    float* out = (float*)d_out;
    float* out_dec  = out;                                   // [B,F]
    float* out_bbn  = out_dec + (size_t)cB * cF;             // [B,L]
    float* out_ci   = out_bbn + (size_t)cB * cL;             // [B,K]
    float* out_feat = out_ci  + (size_t)cB * cK;             // [B,H]
    float* out_adj  = out_feat + (size_t)cB * cH;            // [B,B]

    char* p = (char*)d_ws;
    auto alloc = [&](size_t n) { void* r = p; p += (n + 255) & ~(size_t)255; return r; };
    float* cnorm  = (float*)alloc((size_t)cK * 4);
    float* Svec   = (float*)alloc((size_t)cL * 4);
    float* dinvp  = (float*)alloc((size_t)cB * 4);
    u64* argred   = (u64*)alloc((size_t)cB * 8);
    u64* topbuf   = (u64*)alloc((size_t)cB * 256 * 8);        // [B][128][2]
    bf16* W_gcnt  = (bf16*)alloc((size_t)cL * cL * 2);
    bf16* W_dec1t = (bf16*)alloc((size_t)cH * cL * 2);
    bf16* W_dec2t = (bf16*)alloc((size_t)cF * cH * 2);
    bf16* vnb     = (bf16*)alloc((size_t)cB * cL * 2);
    float* cbn    = (float*)alloc((size_t)cB * cL * 4);
    bf16* cbnst   = (bf16*)alloc((size_t)cL * cB * 2);        // [L][B]
    bf16* tbufb   = (bf16*)alloc((size_t)cB * cL * 2);
    bf16* latentb = (bf16*)alloc((size_t)cB * cL * 2);
    bf16* h1b     = (bf16*)alloc((size_t)cB * cH * 2);
    bf16* adjb    = (bf16*)alloc((size_t)cB * cB * 2);        // bf16 adj copy
    // split-fp16 planes for the fp32-accurate chain
    _Float16* xh     = (_Float16*)alloc((size_t)cB * cF * 2);
    _Float16* xl     = (_Float16*)alloc((size_t)cB * cF * 2);
    _Float16* wet_h  = (_Float16*)alloc((size_t)cH * cF * 2); // W_enc^T planes [H,F]
    _Float16* wet_l  = (_Float16*)alloc((size_t)cH * cF * 2);
    _Float16* feat_h = (_Float16*)alloc((size_t)cB * cH * 2);
    _Float16* feat_l = (_Float16*)alloc((size_t)cB * cH * 2);
    _Float16* wf12t_h = (_Float16*)alloc((size_t)cH * cH * 2); // [W_fc1|W_fc2]^T planes [1024,H]
    _Float16* wf12t_l = (_Float16*)alloc((size_t)cH * cH * 2);
    bf16* bbnb       = (bf16*)alloc((size_t)cB * cL * 2);
    bf16* ctxb       = (bf16*)alloc((size_t)cK * cL * 2);

    dim3 blk(256);

    hipMemsetAsync(out_ci, 0, (size_t)cB * cK * sizeof(float), stream);
    hipMemsetAsync(argred, 0xFF, (size_t)cB * sizeof(u64), stream);
    hipMemsetAsync(Svec, 0, cL * sizeof(float), stream);

    // ---- split operands for fp32-accurate fp16-MFMA chain ----
    split_f16<<<(cB * (size_t)cF) / 2048, blk, 0, stream>>>(x, xh, xl);
    transpose_split<<<dim3(cH / 32, cF / 32), blk, 0, stream>>>(W_enc, wet_h, wet_l, cF, cH);
    // concat [W_fc1 | W_fc2]^T into rows 0-511 / 512-1023 of wf12t planes
    transpose_split<<<dim3(cL / 32, cH / 32), blk, 0, stream>>>(
        W_fc1, wf12t_h, wf12t_l, cH, cL);
    transpose_split<<<dim3(cL / 32, cH / 32), blk, 0, stream>>>(
        W_fc2, wf12t_h + (size_t)cL * cH, wf12t_l + (size_t)cL * cH, cH, cL);

    // ---- feat = relu(x @ W_enc + b_enc)  [fp32-accurate split GEMM] ----
    gemm_sp<64, 1, true, false><<<dim3(cH / 128, cB / 64), blk, 0, stream>>>(
        xh, xl, wet_h, wet_l, b_enc, nullptr, out_feat, nullptr, feat_h, feat_l,
        nullptr, cH, cF);

    // ---- [bbn | cbn] = feat @ [W_fc1|W_fc2] + [b_fc1|b_fc2]  [dual split GEMM] ----
    gemm_sp<64, 0, false, true><<<dim3(cH / 128, cB / 64), blk, 0, stream>>>(
        feat_h, feat_l, wf12t_h, wf12t_l, b_fc1, b_fc2, out_bbn, bbnb,
        nullptr, nullptr, cbn, cH, cH);

    // ---- prep: codebook norms + bf16 copy, weight transposes ----
    rowsumsq_cvt<<<cK, 64, 0, stream>>>(ctx, cnorm, ctxb);
    transpose_cvt<<<dim3(cL / 32, cL / 32), blk, 0, stream>>>(W_gcn, W_gcnt, nullptr, cL, cL);
    transpose_cvt<<<dim3(cH / 32, cL / 32), blk, 0, stream>>>(W_dec1, W_dec1t, nullptr, cL, cH);
    transpose_cvt<<<dim3(cF / 32, cH / 32), blk, 0, stream>>>(W_dec2, W_dec2t, nullptr, cH, cF);

    // ---- coarse distances (bf16 MFMA) + exact argmin resolve ----
    gemm_dist<<<dim3(cK / 128, cB / 128), blk, 0, stream>>>(bbnb, ctxb, cnorm, topbuf, cK, cL);
    dist_resolve<<<cB, blk, 0, stream>>>(topbuf, out_bbn, ctx, cnorm, argred);

    // ---- quantize / normalize / one-hot ----
    gather_vn<<<cB, 64, 0, stream>>>(argred, ctx, vnb, out_ci);
    colsum_b<<<dim3(cL / 256, cB / 256), blk, 0, stream>>>(vnb, Svec);
    dinv_b<<<cB, 64, 0, stream>>>(vnb, Svec, dinvp);

    // ---- adj = (vn @ vn^T + 1) * 0.5  (+ bf16 copy for GCN GEMM) ----
    gemm_bf<128, 3, false, false, true, true>
        <<<dim3(cB / 128, cB / 128), blk, 0, stream>>>(vnb, vnb, nullptr, nullptr, out_adj, adjb, cB, cL);

    // ---- cbnst[l][j] = dinv[j] * cbn[j][l] (bf16 transposed) ----
    transpose_cvt<<<dim3(cL / 32, cB / 32), blk, 0, stream>>>(cbn, cbnst, dinvp, cB, cL);

    // ---- t = dinv[i] * (adj @ cbn_scaled)  (bf16 adj copy) ----
    gemm_bf<64, 0, false, true, false, true>
        <<<dim3(cL / 128, cB / 64), blk, 0, stream>>>(adjb, cbnst, nullptr, dinvp, nullptr, tbufb, cL, cB);

    // ---- latent = sigmoid(t @ W_gcn + b_gcn) ----
    gemm_bf<64, 2, true, false, false, true>
        <<<dim3(cL / 128, cB / 64), blk, 0, stream>>>(tbufb, W_gcnt, b_gcn, nullptr, nullptr, latentb, cL, cL);

    // ---- h1 = relu(latent @ W_dec1 + b_dec1) ----
    gemm_bf<64, 1, true, false, false, true>
        <<<dim3(cH / 128, cB / 64), blk, 0, stream>>>(latentb, W_dec1t, b_dec1, nullptr, nullptr, h1b, cH, cL);

    // ---- decoded = h1 @ W_dec2 + b_dec2 ----
    gemm_bf<128, 0, true, false, true, false>
        <<<dim3(cF / 128, cB / 128), blk, 0, stream>>>(h1b, W_dec2t, b_dec2, nullptr, out_dec, nullptr, cF, cH);
}